// Round 6
// baseline (379.877 us; speedup 1.0000x reference)
//
#include <hip/hip_runtime.h>
#include <hip/hip_fp16.h>

#define NN 50000      // nodes
#define NE 800000     // edges
#define DIM 128       // feature dim (D == H)
#define NG 64         // graphs
#define NOUT 10       // output dim

#define NBKT 391      // coarse buckets: ceil(NN/128), dst>>7
#define HBLK 256      // histogram/scatter blocks
#define CHUNK ((NE + HBLK - 1) / HBLK)   // 3125 edges per block
#define PSLICE 8      // pooling slices per graph

typedef __attribute__((ext_vector_type(8))) short short8;
typedef __attribute__((ext_vector_type(4))) float float4v;

// ---------------------------------------------------------------- pass A1: per-block bucket histogram
__global__ __launch_bounds__(256) void hist_kernel(const int* __restrict__ ei,
                                                   int* __restrict__ blkhist) {
    __shared__ int h[NBKT];
    int b = blockIdx.x;
    for (int i = threadIdx.x; i < NBKT; i += 256) h[i] = 0;
    __syncthreads();
    int lo = b * CHUNK, hi = min(lo + CHUNK, NE);
    for (int e = lo + threadIdx.x; e < hi; e += 256)
        atomicAdd(&h[ei[NE + e] >> 7], 1);  // LDS atomic
    __syncthreads();
    for (int i = threadIdx.x; i < NBKT; i += 256)
        blkhist[b * NBKT + i] = h[i];
}

// ---------------------------------------------------------------- pass A2a: bucket totals
__global__ __launch_bounds__(256) void bintot_kernel(const int* __restrict__ blkhist,
                                                     int* __restrict__ bintot) {
    __shared__ int s[256];
    int bin = blockIdx.x;
    int t = threadIdx.x;
    s[t] = blkhist[t * NBKT + bin];
    __syncthreads();
    #pragma unroll
    for (int off = 128; off > 0; off >>= 1) {
        if (t < off) s[t] += s[t + off];
        __syncthreads();
    }
    if (t == 0) bintot[bin] = s[0];
}

// ---------------------------------------------------------------- pass A2b: scan bucket totals -> bucket_base
__global__ __launch_bounds__(512) void base_scan_kernel(const int* __restrict__ bintot,
                                                        int* __restrict__ bucket_base) {
    __shared__ int s[512];
    int t = threadIdx.x;
    int v = (t < NBKT) ? bintot[t] : 0;
    s[t] = v;
    __syncthreads();
    #pragma unroll
    for (int off = 1; off < 512; off <<= 1) {
        int tv = (t >= off) ? s[t - off] : 0;
        __syncthreads();
        s[t] += tv;
        __syncthreads();
    }
    if (t <= NBKT) bucket_base[t] = s[t] - v;  // exclusive; t==NBKT -> NE
}

// ---------------------------------------------------------------- pass A2c: per-(bucket,block) absolute offsets
__global__ __launch_bounds__(256) void binoff_kernel(int* __restrict__ blkhist,
                                                     const int* __restrict__ bucket_base) {
    __shared__ int s[256];
    int bin = blockIdx.x;
    int t = threadIdx.x;
    int v = blkhist[t * NBKT + bin];
    s[t] = v;
    __syncthreads();
    #pragma unroll
    for (int off = 1; off < 256; off <<= 1) {
        int tv = (t >= off) ? s[t - off] : 0;
        __syncthreads();
        s[t] += tv;
        __syncthreads();
    }
    blkhist[t * NBKT + bin] = bucket_base[bin] + s[t] - v;  // absolute start
}

// ---------------------------------------------------------------- pass A3: scatter edges into buckets (packed)
__global__ __launch_bounds__(256) void bucket_scatter(const int* __restrict__ ei,
                                                      const int* __restrict__ blkhist,
                                                      unsigned* __restrict__ ebuf) {
    __shared__ int cur[NBKT];
    int b = blockIdx.x;
    for (int i = threadIdx.x; i < NBKT; i += 256) cur[i] = blkhist[b * NBKT + i];
    __syncthreads();
    int lo = b * CHUNK, hi = min(lo + CHUNK, NE);
    for (int e = lo + threadIdx.x; e < hi; e += 256) {
        int s = ei[e];
        int d = ei[NE + e];
        int pos = atomicAdd(&cur[d >> 7], 1);  // LDS atomic; block owns disjoint ranges
        ebuf[pos] = ((unsigned)(d & 127) << 16) | (unsigned)s;  // src < 2^16
    }
}

// ---------------------------------------------------------------- pass B: per-bucket CSR build
__global__ __launch_bounds__(128) void build_csr(const unsigned* __restrict__ ebuf,
                                                 const int* __restrict__ bucket_base,
                                                 int* __restrict__ rowoff,
                                                 int* __restrict__ csr_src,
                                                 float* __restrict__ dinv) {
    __shared__ int deg[128];
    __shared__ int loff[128];
    int g = blockIdx.x;
    int lo = bucket_base[g], hi = bucket_base[g + 1];
    int t = threadIdx.x;
    deg[t] = 0;
    __syncthreads();
    for (int p = lo + t; p < hi; p += 128)
        atomicAdd(&deg[ebuf[p] >> 16], 1);
    __syncthreads();
    int v = deg[t];
    loff[t] = v;
    __syncthreads();
    #pragma unroll
    for (int off = 1; off < 128; off <<= 1) {
        int tv = (t >= off) ? loff[t - off] : 0;
        __syncthreads();
        loff[t] += tv;
        __syncthreads();
    }
    int excl = loff[t] - v;
    int node = g * 128 + t;
    if (node < NN) {
        rowoff[node] = lo + excl;
        dinv[node] = 1.0f / sqrtf((float)v + 1.0f);
    }
    if (node == 0) rowoff[NN] = NE;
    deg[t] = lo + excl;  // reuse as cursor
    __syncthreads();
    for (int p = lo + t; p < hi; p += 128) {
        unsigned pk = ebuf[p];
        int pos = atomicAdd(&deg[pk >> 16], 1);
        csr_src[pos] = (int)(pk & 0xFFFFu);
    }
}

// ---------------------------------------------------------------- graph boundaries (batch is sorted)
__global__ __launch_bounds__(128) void bounds_kernel(const int* __restrict__ batch,
                                                     int* __restrict__ first) {
    int g = threadIdx.x;
    if (g <= NG) {
        int lo = 0, hi = NN;
        while (lo < hi) {
            int mid = (lo + hi) >> 1;
            if (batch[mid] < g) lo = mid + 1; else hi = mid;
        }
        first[g] = lo;  // lower_bound(batch, g)
    }
}

// ---------------------------------------------------------------- W prep: f32 [k][n] -> bf16 hi/lo transposed [n][k]
__global__ __launch_bounds__(256) void wprep_kernel(const float* __restrict__ W0,
                                                    const float* __restrict__ W1,
                                                    const float* __restrict__ W2,
                                                    short* __restrict__ out) {
    int w = blockIdx.x >> 4;
    int sub = blockIdx.x & 15;
    const float* W = (w == 0) ? W0 : (w == 1) ? W1 : W2;
    short* Wh = out + w * 2 * DIM * DIM;
    short* Wl = Wh + DIM * DIM;
    #pragma unroll
    for (int t = 0; t < 4; ++t) {
        int idx = sub * 1024 + t * 256 + threadIdx.x;
        int k = idx >> 7, n = idx & 127;
        float v = W[idx];
        unsigned u = __float_as_uint(v);
        unsigned hb = (u + 0x7FFFu + ((u >> 16) & 1u)) & 0xFFFF0000u;  // RNE bf16
        float res = v - __uint_as_float(hb);
        unsigned u2 = __float_as_uint(res);
        unsigned lb = (u2 + 0x7FFFu + ((u2 >> 16) & 1u)) >> 16;
        Wh[n * DIM + k] = (short)(hb >> 16);
        Wl[n * DIM + k] = (short)lb;
    }
}

// ---------------------------------------------------------------- GEMM: Y(fp16) = op(X) @ W, LDS-free split-bf16 MFMA
// 3-term split: x*w = xh*wh + xl*wh + xh*wl. B-frags straight from L1/L2
// (W hi+lo = 64 KB, fully L2-resident). No barriers; fp16 output halves
// the gather bytes for agg.
template <bool RELU>
__global__ __launch_bounds__(256) void gemm_mfma(const float* __restrict__ X,
                                                 const short* __restrict__ Wsp,
                                                 __half* __restrict__ Y, int nrows) {
    int tid = threadIdx.x;
    int wave = tid >> 6;
    int lane = tid & 63;
    int lm = lane & 15;   // A row within tile / B col within tile / D col
    int lq = lane >> 4;   // k-octet selector / D row-quad
    int row0 = blockIdx.x * 64 + wave * 16;
    int rr = min(row0 + lm, nrows - 1);
    const float* Xp = X + (size_t)rr * DIM + lq * 8;
    const short* Wh = Wsp;             // [n][k]
    // Wl at Wsp + DIM*DIM

    float4v acc[8];
    #pragma unroll
    for (int i = 0; i < 8; ++i) acc[i] = (float4v){0.f, 0.f, 0.f, 0.f};

    #pragma unroll
    for (int kk = 0; kk < 4; ++kk) {
        float4 xa = *(const float4*)(Xp + kk * 32);
        float4 xb = *(const float4*)(Xp + kk * 32 + 4);
        float xv[8] = {xa.x, xa.y, xa.z, xa.w, xb.x, xb.y, xb.z, xb.w};
        short8 ah, al;
        #pragma unroll
        for (int j = 0; j < 8; ++j) {
            float v = xv[j];
            if (RELU) v = fmaxf(v, 0.0f);
            unsigned u = __float_as_uint(v);
            unsigned hb = (u + 0x7FFFu + ((u >> 16) & 1u)) & 0xFFFF0000u;
            float res = v - __uint_as_float(hb);
            unsigned u2 = __float_as_uint(res);
            unsigned lb = (u2 + 0x7FFFu + ((u2 >> 16) & 1u)) >> 16;
            ah[j] = (short)(hb >> 16);
            al[j] = (short)lb;
        }
        #pragma unroll
        for (int n0 = 0; n0 < 8; ++n0) {
            const short* bp = Wh + (n0 * 16 + lm) * DIM + kk * 32 + lq * 8;
            short8 bh = *(const short8*)bp;
            short8 bl = *(const short8*)(bp + DIM * DIM);
            acc[n0] = __builtin_amdgcn_mfma_f32_16x16x32_bf16(ah, bh, acc[n0], 0, 0, 0);
            acc[n0] = __builtin_amdgcn_mfma_f32_16x16x32_bf16(al, bh, acc[n0], 0, 0, 0);
            acc[n0] = __builtin_amdgcn_mfma_f32_16x16x32_bf16(ah, bl, acc[n0], 0, 0, 0);
        }
    }
    // D layout: col = lane&15, row = (lane>>4)*4 + reg  [verified m89/m91]
    #pragma unroll
    for (int n0 = 0; n0 < 8; ++n0) {
        #pragma unroll
        for (int rg = 0; rg < 4; ++rg) {
            int row = row0 + lq * 4 + rg;
            if (row < nrows) Y[(size_t)row * DIM + n0 * 16 + lm] = __float2half(acc[n0][rg]);
        }
    }
}

// ---------------------------------------------------------------- aggregation (CSR, fp16 256 B row gathers)
union U4 { ushort4 u; __half h[4]; };

__global__ __launch_bounds__(128) void agg_kernel(const __half* __restrict__ H,
                                                  float* __restrict__ O,
                                                  const int* __restrict__ rowoff,
                                                  const int* __restrict__ csr_src,
                                                  const float* __restrict__ dinv) {
    __shared__ float part[4][DIM];
    int i = blockIdx.x;
    int tid = threadIdx.x;
    int grp = tid >> 5, ln = tid & 31;
    int s = rowoff[i], e = rowoff[i + 1];
    const __half* Hc = H + ln * 4;  // lane covers 4 fp16 = 8 B; 32 lanes = 256 B row

    float a0 = 0.f, a1 = 0.f, a2 = 0.f, a3 = 0.f;
#define ACC4(Q, D) { U4 w_; w_.u = (Q); \
    a0 = fmaf((D), __half2float(w_.h[0]), a0); \
    a1 = fmaf((D), __half2float(w_.h[1]), a1); \
    a2 = fmaf((D), __half2float(w_.h[2]), a2); \
    a3 = fmaf((D), __half2float(w_.h[3]), a3); }

    int p = s + grp;
    for (; p + 12 < e; p += 16) {
        int u0 = csr_src[p];
        int u1 = csr_src[p + 4];
        int u2 = csr_src[p + 8];
        int u3 = csr_src[p + 12];
        float d0 = dinv[u0], d1 = dinv[u1], d2 = dinv[u2], d3 = dinv[u3];
        ushort4 q0 = *(const ushort4*)(Hc + (size_t)u0 * DIM);
        ushort4 q1 = *(const ushort4*)(Hc + (size_t)u1 * DIM);
        ushort4 q2 = *(const ushort4*)(Hc + (size_t)u2 * DIM);
        ushort4 q3 = *(const ushort4*)(Hc + (size_t)u3 * DIM);
        ACC4(q0, d0); ACC4(q1, d1); ACC4(q2, d2); ACC4(q3, d3);
    }
    for (; p < e; p += 4) {
        int u = csr_src[p];
        float d = dinv[u];
        ushort4 q = *(const ushort4*)(Hc + (size_t)u * DIM);
        ACC4(q, d);
    }
#undef ACC4
    *(float4*)&part[grp][ln * 4] = make_float4(a0, a1, a2, a3);
    __syncthreads();
    // thread tid finalizes column tid
    float di = dinv[i];
    float tot = part[0][tid] + part[1][tid] + part[2][tid] + part[3][tid];
    tot = fmaf(di, __half2float(H[(size_t)i * DIM + tid]), tot);  // self-loop
    O[(size_t)i * DIM + tid] = di * tot;
}

// ---------------------------------------------------------------- pooling stage 1: per-(graph,slice) partials
__global__ __launch_bounds__(128) void pool_part(const float* __restrict__ H,
                                                 const int* __restrict__ first,
                                                 float* __restrict__ ppart) {
    __shared__ float part[4][DIM];
    int g = blockIdx.x;
    int sl = blockIdx.y;
    int tid = threadIdx.x;
    int rg = tid >> 5, ln = tid & 31;
    int s = first[g], e = first[g + 1];
    float4 acc = make_float4(0.f, 0.f, 0.f, 0.f);
    for (int r = s + sl * 4 + rg; r < e; r += PSLICE * 4) {
        float4 h = *(const float4*)(H + (size_t)r * DIM + ln * 4);
        acc.x += h.x; acc.y += h.y; acc.z += h.z; acc.w += h.w;
    }
    *(float4*)&part[rg][ln * 4] = acc;
    __syncthreads();
    float tot = part[0][tid] + part[1][tid] + part[2][tid] + part[3][tid];
    ppart[(size_t)(g * PSLICE + sl) * DIM + tid] = tot;
}

// ---------------------------------------------------------------- pool reduce + MLP (fused)
__global__ __launch_bounds__(128) void mlp_kernel(const float* __restrict__ ppart,
                                                  const int* __restrict__ first,
                                                  const float* __restrict__ M0w,
                                                  const float* __restrict__ M0b,
                                                  const float* __restrict__ M1w,
                                                  const float* __restrict__ M1b,
                                                  float* __restrict__ out) {
    __shared__ float p[DIM];
    __shared__ float t[DIM];
    int g = blockIdx.x;
    int j = threadIdx.x;
    float tot = 0.f;
    #pragma unroll
    for (int sl = 0; sl < PSLICE; ++sl)
        tot += ppart[(size_t)(g * PSLICE + sl) * DIM + j];
    float cnt = (float)max(first[g + 1] - first[g], 1);
    p[j] = tot / cnt;
    __syncthreads();
    float acc = M0b[j];
    #pragma unroll 8
    for (int k = 0; k < DIM; ++k) acc = fmaf(p[k], M0w[k * DIM + j], acc);
    t[j] = fmaxf(acc, 0.0f);
    __syncthreads();
    if (j < NOUT) {
        float o = M1b[j];
        #pragma unroll 8
        for (int k = 0; k < DIM; ++k) o = fmaf(t[k], M1w[k * NOUT + j], o);
        out[g * NOUT + j] = o;
    }
}

// ---------------------------------------------------------------- launcher
extern "C" void kernel_launch(void* const* d_in, const int* in_sizes, int n_in,
                              void* d_out, int out_size, void* d_ws, size_t ws_size,
                              hipStream_t stream) {
    const float* x   = (const float*)d_in[0];
    const float* W0  = (const float*)d_in[1];
    const float* W1  = (const float*)d_in[2];
    const float* W2  = (const float*)d_in[3];
    const float* M0w = (const float*)d_in[4];
    const float* M0b = (const float*)d_in[5];
    const float* M1w = (const float*)d_in[6];
    const float* M1b = (const float*)d_in[7];
    const int* ei    = (const int*)d_in[8];
    const int* batch = (const int*)d_in[9];
    float* out = (float*)d_out;

    char* ws = (char*)d_ws;
    size_t off = 0;
    auto take = [&](size_t bytes) -> void* {
        void* p = ws + off;
        off = (off + bytes + 255) & ~(size_t)255;
        return p;
    };
    __half* hA   = (__half*)take((size_t)NN * DIM * 2);   // fp16 GEMM output (gathered)
    float* hB    = (float*)take((size_t)NN * DIM * 4);    // f32 agg output (GEMM input)
    unsigned* ebuf = (unsigned*)take((size_t)NE * 4);
    int* csr_src = (int*)take((size_t)NE * 4);
    int* blkhist = (int*)take((size_t)HBLK * NBKT * 4);
    int* bintot  = (int*)take((size_t)NBKT * 4);
    int* bucket_base = (int*)take((size_t)(NBKT + 1) * 4);
    int* rowoff  = (int*)take((size_t)(NN + 1) * 4);
    float* dinv  = (float*)take((size_t)NN * 4);
    int* first   = (int*)take((size_t)(NG + 1) * 4);
    float* ppart = (float*)take((size_t)NG * PSLICE * DIM * 4);
    short* wsp   = (short*)take((size_t)3 * 2 * DIM * DIM * 2);
    (void)ws_size; (void)in_sizes; (void)n_in; (void)out_size;

    // ---- weight split (bf16 hi/lo, transposed) + CSR build
    wprep_kernel<<<48, 256, 0, stream>>>(W0, W1, W2, wsp);
    hist_kernel<<<HBLK, 256, 0, stream>>>(ei, blkhist);
    bintot_kernel<<<NBKT, 256, 0, stream>>>(blkhist, bintot);
    base_scan_kernel<<<1, 512, 0, stream>>>(bintot, bucket_base);
    binoff_kernel<<<NBKT, 256, 0, stream>>>(blkhist, bucket_base);
    bucket_scatter<<<HBLK, 256, 0, stream>>>(ei, blkhist, ebuf);
    build_csr<<<NBKT, 128, 0, stream>>>(ebuf, bucket_base, rowoff, csr_src, dinv);
    bounds_kernel<<<1, 128, 0, stream>>>(batch, first);

    // ---- 3x (GEMM -> aggregate)
    const int GB = (NN + 63) / 64;
    gemm_mfma<false><<<GB, 256, 0, stream>>>(x, wsp, hA, NN);
    agg_kernel<<<NN, 128, 0, stream>>>(hA, hB, rowoff, csr_src, dinv);
    gemm_mfma<true><<<GB, 256, 0, stream>>>(hB, wsp + 2 * DIM * DIM, hA, NN);
    agg_kernel<<<NN, 128, 0, stream>>>(hA, hB, rowoff, csr_src, dinv);
    gemm_mfma<true><<<GB, 256, 0, stream>>>(hB, wsp + 4 * DIM * DIM, hA, NN);
    agg_kernel<<<NN, 128, 0, stream>>>(hA, hB, rowoff, csr_src, dinv);

    // ---- pool + MLP (atomic-free two-stage, stage 2 fused into MLP)
    dim3 pgrid(NG, PSLICE);
    pool_part<<<pgrid, 128, 0, stream>>>(hB, first, ppart);
    mlp_kernel<<<NG, 128, 0, stream>>>(ppart, first, M0w, M0b, M1w, M1b, out);
}

// Round 7
// 319.769 us; speedup vs baseline: 1.1880x; 1.1880x over previous
//
#include <hip/hip_runtime.h>
#include <hip/hip_fp16.h>

#define NN 50000      // nodes
#define NE 800000     // edges
#define DIM 128       // feature dim (D == H)
#define NG 64         // graphs
#define NOUT 10       // output dim

#define NBKT 391      // coarse buckets: ceil(NN/128), dst>>7
#define HBLK 256      // histogram/scatter blocks
#define CHUNK ((NE + HBLK - 1) / HBLK)   // 3125 edges per block
#define PSLICE 8      // pooling slices per graph

typedef __attribute__((ext_vector_type(8))) short short8;
typedef __attribute__((ext_vector_type(4))) float float4v;

__device__ __forceinline__ void bf16_split(float v, short& hi, short& lo) {
    unsigned u = __float_as_uint(v);
    unsigned hb = (u + 0x7FFFu + ((u >> 16) & 1u)) & 0xFFFF0000u;  // RNE bf16
    float res = v - __uint_as_float(hb);
    unsigned u2 = __float_as_uint(res);
    unsigned lb = (u2 + 0x7FFFu + ((u2 >> 16) & 1u)) >> 16;
    hi = (short)(hb >> 16);
    lo = (short)lb;
}

// ---------------------------------------------------------------- pass A1: per-block bucket histogram
__global__ __launch_bounds__(256) void hist_kernel(const int* __restrict__ ei,
                                                   int* __restrict__ blkhist) {
    __shared__ int h[NBKT];
    int b = blockIdx.x;
    for (int i = threadIdx.x; i < NBKT; i += 256) h[i] = 0;
    __syncthreads();
    int lo = b * CHUNK, hi = min(lo + CHUNK, NE);
    for (int e = lo + threadIdx.x; e < hi; e += 256)
        atomicAdd(&h[ei[NE + e] >> 7], 1);  // LDS atomic
    __syncthreads();
    for (int i = threadIdx.x; i < NBKT; i += 256)
        blkhist[b * NBKT + i] = h[i];
}

// ---------------------------------------------------------------- pass A2a: bucket totals
__global__ __launch_bounds__(256) void bintot_kernel(const int* __restrict__ blkhist,
                                                     int* __restrict__ bintot) {
    __shared__ int s[256];
    int bin = blockIdx.x;
    int t = threadIdx.x;
    s[t] = blkhist[t * NBKT + bin];
    __syncthreads();
    #pragma unroll
    for (int off = 128; off > 0; off >>= 1) {
        if (t < off) s[t] += s[t + off];
        __syncthreads();
    }
    if (t == 0) bintot[bin] = s[0];
}

// ---------------------------------------------------------------- pass A2b: scan bucket totals -> bucket_base
__global__ __launch_bounds__(512) void base_scan_kernel(const int* __restrict__ bintot,
                                                        int* __restrict__ bucket_base) {
    __shared__ int s[512];
    int t = threadIdx.x;
    int v = (t < NBKT) ? bintot[t] : 0;
    s[t] = v;
    __syncthreads();
    #pragma unroll
    for (int off = 1; off < 512; off <<= 1) {
        int tv = (t >= off) ? s[t - off] : 0;
        __syncthreads();
        s[t] += tv;
        __syncthreads();
    }
    if (t <= NBKT) bucket_base[t] = s[t] - v;  // exclusive; t==NBKT -> NE
}

// ---------------------------------------------------------------- pass A2c: per-(bucket,block) absolute offsets
__global__ __launch_bounds__(256) void binoff_kernel(int* __restrict__ blkhist,
                                                     const int* __restrict__ bucket_base) {
    __shared__ int s[256];
    int bin = blockIdx.x;
    int t = threadIdx.x;
    int v = blkhist[t * NBKT + bin];
    s[t] = v;
    __syncthreads();
    #pragma unroll
    for (int off = 1; off < 256; off <<= 1) {
        int tv = (t >= off) ? s[t - off] : 0;
        __syncthreads();
        s[t] += tv;
        __syncthreads();
    }
    blkhist[t * NBKT + bin] = bucket_base[bin] + s[t] - v;  // absolute start
}

// ---------------------------------------------------------------- pass A3: scatter edges into buckets (packed)
__global__ __launch_bounds__(256) void bucket_scatter(const int* __restrict__ ei,
                                                      const int* __restrict__ blkhist,
                                                      unsigned* __restrict__ ebuf) {
    __shared__ int cur[NBKT];
    int b = blockIdx.x;
    for (int i = threadIdx.x; i < NBKT; i += 256) cur[i] = blkhist[b * NBKT + i];
    __syncthreads();
    int lo = b * CHUNK, hi = min(lo + CHUNK, NE);
    for (int e = lo + threadIdx.x; e < hi; e += 256) {
        int s = ei[e];
        int d = ei[NE + e];
        int pos = atomicAdd(&cur[d >> 7], 1);  // LDS atomic; block owns disjoint ranges
        ebuf[pos] = ((unsigned)(d & 127) << 16) | (unsigned)s;  // src < 2^16
    }
}

// ---------------------------------------------------------------- pass B: per-bucket CSR build
__global__ __launch_bounds__(128) void build_csr(const unsigned* __restrict__ ebuf,
                                                 const int* __restrict__ bucket_base,
                                                 int* __restrict__ rowoff,
                                                 int* __restrict__ csr_src,
                                                 float* __restrict__ dinv) {
    __shared__ int deg[128];
    __shared__ int loff[128];
    int g = blockIdx.x;
    int lo = bucket_base[g], hi = bucket_base[g + 1];
    int t = threadIdx.x;
    deg[t] = 0;
    __syncthreads();
    for (int p = lo + t; p < hi; p += 128)
        atomicAdd(&deg[ebuf[p] >> 16], 1);
    __syncthreads();
    int v = deg[t];
    loff[t] = v;
    __syncthreads();
    #pragma unroll
    for (int off = 1; off < 128; off <<= 1) {
        int tv = (t >= off) ? loff[t - off] : 0;
        __syncthreads();
        loff[t] += tv;
        __syncthreads();
    }
    int excl = loff[t] - v;
    int node = g * 128 + t;
    if (node < NN) {
        rowoff[node] = lo + excl;
        dinv[node] = 1.0f / sqrtf((float)v + 1.0f);
    }
    if (node == 0) rowoff[NN] = NE;
    deg[t] = lo + excl;  // reuse as cursor
    __syncthreads();
    for (int p = lo + t; p < hi; p += 128) {
        unsigned pk = ebuf[p];
        int pos = atomicAdd(&deg[pk >> 16], 1);
        csr_src[pos] = (int)(pk & 0xFFFFu);
    }
}

// ---------------------------------------------------------------- graph boundaries (batch is sorted)
__global__ __launch_bounds__(128) void bounds_kernel(const int* __restrict__ batch,
                                                     int* __restrict__ first) {
    int g = threadIdx.x;
    if (g <= NG) {
        int lo = 0, hi = NN;
        while (lo < hi) {
            int mid = (lo + hi) >> 1;
            if (batch[mid] < g) lo = mid + 1; else hi = mid;
        }
        first[g] = lo;  // lower_bound(batch, g)
    }
}

// ---------------------------------------------------------------- W prep: f32 [k][n] -> bf16 hi/lo transposed [n][k]
__global__ __launch_bounds__(256) void wprep_kernel(const float* __restrict__ W0,
                                                    const float* __restrict__ W1,
                                                    const float* __restrict__ W2,
                                                    short* __restrict__ out) {
    int w = blockIdx.x >> 4;
    int sub = blockIdx.x & 15;
    const float* W = (w == 0) ? W0 : (w == 1) ? W1 : W2;
    short* Wh = out + w * 2 * DIM * DIM;
    short* Wl = Wh + DIM * DIM;
    #pragma unroll
    for (int t = 0; t < 4; ++t) {
        int idx = sub * 1024 + t * 256 + threadIdx.x;
        int k = idx >> 7, n = idx & 127;
        short hi, lo;
        bf16_split(W[idx], hi, lo);
        Wh[n * DIM + k] = hi;
        Wl[n * DIM + k] = lo;
    }
}

// ---------------------------------------------------------------- x prep: f32 -> bf16 hi/lo planes (same layout)
// grid = NN*DIM/2048 = 3125 blocks x 256 threads x 8 elems
__global__ __launch_bounds__(256) void xsplit_kernel(const float* __restrict__ X,
                                                     short* __restrict__ Ahi,
                                                     short* __restrict__ Alo) {
    size_t base = (size_t)blockIdx.x * 2048;
    #pragma unroll
    for (int c = 0; c < 2; ++c) {
        size_t idx = base + c * 1024 + threadIdx.x * 4;
        float4 v = *(const float4*)(X + idx);
        short h0, l0, h1, l1, h2, l2, h3, l3;
        bf16_split(v.x, h0, l0);
        bf16_split(v.y, h1, l1);
        bf16_split(v.z, h2, l2);
        bf16_split(v.w, h3, l3);
        ushort4 hv = make_ushort4((unsigned short)h0, (unsigned short)h1,
                                  (unsigned short)h2, (unsigned short)h3);
        ushort4 lv = make_ushort4((unsigned short)l0, (unsigned short)l1,
                                  (unsigned short)l2, (unsigned short)l3);
        *(ushort4*)(Ahi + idx) = hv;
        *(ushort4*)(Alo + idx) = lv;
    }
}

// ---------------------------------------------------------------- GEMM: Y(fp16) = A @ W, pre-split bf16 MFMA
// A is pre-split into hi/lo planes (relu already applied upstream).
// 3-term: ah*bh + al*bh + ah*bl. 128-row blocks, W staged in LDS once.
#define WPAD 136  // LDS row stride in shorts
__global__ __launch_bounds__(256) void gemm_mfma(const short* __restrict__ Ahi,
                                                 const short* __restrict__ Alo,
                                                 const short* __restrict__ Wsp,
                                                 __half* __restrict__ Y, int nrows) {
    __shared__ short Wh[DIM * WPAD];
    __shared__ short Wl[DIM * WPAD];
    int tid = threadIdx.x;
    {
        const short8* gh = (const short8*)Wsp;                // [n][k], 2048 short8
        const short8* gl = (const short8*)(Wsp + DIM * DIM);
        #pragma unroll
        for (int i = 0; i < 8; ++i) {
            int e = tid + 256 * i;        // short8 index
            int n = e >> 4;
            int k = (e & 15) * 8;
            *(short8*)&Wh[n * WPAD + k] = gh[e];
            *(short8*)&Wl[n * WPAD + k] = gl[e];
        }
    }
    int wave = tid >> 6;
    int lane = tid & 63;
    int lm = lane & 15;   // A row within tile / B col within tile / D col
    int lq = lane >> 4;   // k-octet selector / D row-quad
    int row_t0 = blockIdx.x * 128 + wave * 32;  // this wave: rows [row_t0, row_t0+32)

    float4v acc[2][8];
    #pragma unroll
    for (int t = 0; t < 2; ++t)
        #pragma unroll
        for (int i = 0; i < 8; ++i) acc[t][i] = (float4v){0.f, 0.f, 0.f, 0.f};

    __syncthreads();
    #pragma unroll
    for (int kk = 0; kk < 4; ++kk) {
        short8 ah[2], al[2];
        #pragma unroll
        for (int t = 0; t < 2; ++t) {
            int r = min(row_t0 + t * 16 + lm, nrows - 1);
            size_t ao = (size_t)r * DIM + kk * 32 + lq * 8;
            ah[t] = *(const short8*)(Ahi + ao);
            al[t] = *(const short8*)(Alo + ao);
        }
        #pragma unroll
        for (int n0 = 0; n0 < 8; ++n0) {
            const short* bp = &Wh[(n0 * 16 + lm) * WPAD + kk * 32 + lq * 8];
            short8 bh = *(const short8*)bp;
            short8 bl = *(const short8*)&Wl[(n0 * 16 + lm) * WPAD + kk * 32 + lq * 8];
            #pragma unroll
            for (int t = 0; t < 2; ++t) {
                acc[t][n0] = __builtin_amdgcn_mfma_f32_16x16x32_bf16(ah[t], bh, acc[t][n0], 0, 0, 0);
                acc[t][n0] = __builtin_amdgcn_mfma_f32_16x16x32_bf16(al[t], bh, acc[t][n0], 0, 0, 0);
                acc[t][n0] = __builtin_amdgcn_mfma_f32_16x16x32_bf16(ah[t], bl, acc[t][n0], 0, 0, 0);
            }
        }
    }
    // D layout: col = lane&15, row = (lane>>4)*4 + reg  [verified m89/m91]
    #pragma unroll
    for (int t = 0; t < 2; ++t)
        #pragma unroll
        for (int n0 = 0; n0 < 8; ++n0)
            #pragma unroll
            for (int rg = 0; rg < 4; ++rg) {
                int row = row_t0 + t * 16 + lq * 4 + rg;
                if (row < nrows) Y[(size_t)row * DIM + n0 * 16 + lm] = __float2half(acc[t][n0][rg]);
            }
}

// ---------------------------------------------------------------- aggregation (CSR, fp16 gathers)
// SPLIT: write relu'd bf16 hi/lo planes (next GEMM's A). else: f32 (pool input).
union U4 { ushort4 u; __half h[4]; };

template <bool SPLIT>
__global__ __launch_bounds__(128) void agg_kernel(const __half* __restrict__ H,
                                                  float* __restrict__ O,
                                                  short* __restrict__ Ohi,
                                                  short* __restrict__ Olo,
                                                  const int* __restrict__ rowoff,
                                                  const int* __restrict__ csr_src,
                                                  const float* __restrict__ dinv) {
    __shared__ float part[4][DIM];
    int i = blockIdx.x;
    int tid = threadIdx.x;
    int grp = tid >> 5, ln = tid & 31;
    int s = rowoff[i], e = rowoff[i + 1];
    const __half* Hc = H + ln * 4;  // lane covers 4 fp16 = 8 B; 32 lanes = 256 B row

    float a0 = 0.f, a1 = 0.f, a2 = 0.f, a3 = 0.f;
#define ACC4(Q, D) { U4 w_; w_.u = (Q); \
    a0 = fmaf((D), __half2float(w_.h[0]), a0); \
    a1 = fmaf((D), __half2float(w_.h[1]), a1); \
    a2 = fmaf((D), __half2float(w_.h[2]), a2); \
    a3 = fmaf((D), __half2float(w_.h[3]), a3); }

    int p = s + grp;
    for (; p + 12 < e; p += 16) {
        int u0 = csr_src[p];
        int u1 = csr_src[p + 4];
        int u2 = csr_src[p + 8];
        int u3 = csr_src[p + 12];
        float d0 = dinv[u0], d1 = dinv[u1], d2 = dinv[u2], d3 = dinv[u3];
        ushort4 q0 = *(const ushort4*)(Hc + (size_t)u0 * DIM);
        ushort4 q1 = *(const ushort4*)(Hc + (size_t)u1 * DIM);
        ushort4 q2 = *(const ushort4*)(Hc + (size_t)u2 * DIM);
        ushort4 q3 = *(const ushort4*)(Hc + (size_t)u3 * DIM);
        ACC4(q0, d0); ACC4(q1, d1); ACC4(q2, d2); ACC4(q3, d3);
    }
    for (; p < e; p += 4) {
        int u = csr_src[p];
        float d = dinv[u];
        ushort4 q = *(const ushort4*)(Hc + (size_t)u * DIM);
        ACC4(q, d);
    }
#undef ACC4
    *(float4*)&part[grp][ln * 4] = make_float4(a0, a1, a2, a3);
    __syncthreads();
    // thread tid finalizes column tid
    float di = dinv[i];
    float tot = part[0][tid] + part[1][tid] + part[2][tid] + part[3][tid];
    tot = fmaf(di, __half2float(H[(size_t)i * DIM + tid]), tot);  // self-loop
    float v = di * tot;
    if (SPLIT) {
        v = fmaxf(v, 0.0f);  // relu fused (reference applies relu before next conv)
        short hi, lo;
        bf16_split(v, hi, lo);
        Ohi[(size_t)i * DIM + tid] = hi;
        Olo[(size_t)i * DIM + tid] = lo;
    } else {
        O[(size_t)i * DIM + tid] = v;
    }
}

// ---------------------------------------------------------------- pooling stage 1: per-(graph,slice) partials
__global__ __launch_bounds__(128) void pool_part(const float* __restrict__ H,
                                                 const int* __restrict__ first,
                                                 float* __restrict__ ppart) {
    __shared__ float part[4][DIM];
    int g = blockIdx.x;
    int sl = blockIdx.y;
    int tid = threadIdx.x;
    int rg = tid >> 5, ln = tid & 31;
    int s = first[g], e = first[g + 1];
    float4 acc = make_float4(0.f, 0.f, 0.f, 0.f);
    for (int r = s + sl * 4 + rg; r < e; r += PSLICE * 4) {
        float4 h = *(const float4*)(H + (size_t)r * DIM + ln * 4);
        acc.x += h.x; acc.y += h.y; acc.z += h.z; acc.w += h.w;
    }
    *(float4*)&part[rg][ln * 4] = acc;
    __syncthreads();
    float tot = part[0][tid] + part[1][tid] + part[2][tid] + part[3][tid];
    ppart[(size_t)(g * PSLICE + sl) * DIM + tid] = tot;
}

// ---------------------------------------------------------------- pool reduce + MLP (fused)
__global__ __launch_bounds__(128) void mlp_kernel(const float* __restrict__ ppart,
                                                  const int* __restrict__ first,
                                                  const float* __restrict__ M0w,
                                                  const float* __restrict__ M0b,
                                                  const float* __restrict__ M1w,
                                                  const float* __restrict__ M1b,
                                                  float* __restrict__ out) {
    __shared__ float p[DIM];
    __shared__ float t[DIM];
    int g = blockIdx.x;
    int j = threadIdx.x;
    float tot = 0.f;
    #pragma unroll
    for (int sl = 0; sl < PSLICE; ++sl)
        tot += ppart[(size_t)(g * PSLICE + sl) * DIM + j];
    float cnt = (float)max(first[g + 1] - first[g], 1);
    p[j] = tot / cnt;
    __syncthreads();
    float acc = M0b[j];
    #pragma unroll 8
    for (int k = 0; k < DIM; ++k) acc = fmaf(p[k], M0w[k * DIM + j], acc);
    t[j] = fmaxf(acc, 0.0f);
    __syncthreads();
    if (j < NOUT) {
        float o = M1b[j];
        #pragma unroll 8
        for (int k = 0; k < DIM; ++k) o = fmaf(t[k], M1w[k * NOUT + j], o);
        out[g * NOUT + j] = o;
    }
}

// ---------------------------------------------------------------- launcher
extern "C" void kernel_launch(void* const* d_in, const int* in_sizes, int n_in,
                              void* d_out, int out_size, void* d_ws, size_t ws_size,
                              hipStream_t stream) {
    const float* x   = (const float*)d_in[0];
    const float* W0  = (const float*)d_in[1];
    const float* W1  = (const float*)d_in[2];
    const float* W2  = (const float*)d_in[3];
    const float* M0w = (const float*)d_in[4];
    const float* M0b = (const float*)d_in[5];
    const float* M1w = (const float*)d_in[6];
    const float* M1b = (const float*)d_in[7];
    const int* ei    = (const int*)d_in[8];
    const int* batch = (const int*)d_in[9];
    float* out = (float*)d_out;

    char* ws = (char*)d_ws;
    size_t off = 0;
    auto take = [&](size_t bytes) -> void* {
        void* p = ws + off;
        off = (off + bytes + 255) & ~(size_t)255;
        return p;
    };
    __half* hA   = (__half*)take((size_t)NN * DIM * 2);   // fp16 GEMM output (gathered)
    float* hB    = (float*)take((size_t)NN * DIM * 4);    // f32 agg3 output (pool input)
    short* Ahi   = (short*)take((size_t)NN * DIM * 2);    // bf16-hi plane (GEMM A)
    short* Alo   = (short*)take((size_t)NN * DIM * 2);    // bf16-lo plane
    unsigned* ebuf = (unsigned*)take((size_t)NE * 4);
    int* csr_src = (int*)take((size_t)NE * 4);
    int* blkhist = (int*)take((size_t)HBLK * NBKT * 4);
    int* bintot  = (int*)take((size_t)NBKT * 4);
    int* bucket_base = (int*)take((size_t)(NBKT + 1) * 4);
    int* rowoff  = (int*)take((size_t)(NN + 1) * 4);
    float* dinv  = (float*)take((size_t)NN * 4);
    int* first   = (int*)take((size_t)(NG + 1) * 4);
    float* ppart = (float*)take((size_t)NG * PSLICE * DIM * 4);
    short* wsp   = (short*)take((size_t)3 * 2 * DIM * DIM * 2);
    (void)ws_size; (void)in_sizes; (void)n_in; (void)out_size;

    // ---- prep: weight split, x split, CSR build
    wprep_kernel<<<48, 256, 0, stream>>>(W0, W1, W2, wsp);
    xsplit_kernel<<<NN * DIM / 2048, 256, 0, stream>>>(x, Ahi, Alo);
    hist_kernel<<<HBLK, 256, 0, stream>>>(ei, blkhist);
    bintot_kernel<<<NBKT, 256, 0, stream>>>(blkhist, bintot);
    base_scan_kernel<<<1, 512, 0, stream>>>(bintot, bucket_base);
    binoff_kernel<<<NBKT, 256, 0, stream>>>(blkhist, bucket_base);
    bucket_scatter<<<HBLK, 256, 0, stream>>>(ei, blkhist, ebuf);
    build_csr<<<NBKT, 128, 0, stream>>>(ebuf, bucket_base, rowoff, csr_src, dinv);
    bounds_kernel<<<1, 128, 0, stream>>>(batch, first);

    // ---- 3x (GEMM -> aggregate); agg1/agg2 emit relu'd split planes in-place
    const int GB = (NN + 127) / 128;  // 391 gemm blocks
    gemm_mfma<<<GB, 256, 0, stream>>>(Ahi, Alo, wsp, hA, NN);
    agg_kernel<true><<<NN, 128, 0, stream>>>(hA, nullptr, Ahi, Alo, rowoff, csr_src, dinv);
    gemm_mfma<<<GB, 256, 0, stream>>>(Ahi, Alo, wsp + 2 * DIM * DIM, hA, NN);
    agg_kernel<true><<<NN, 128, 0, stream>>>(hA, nullptr, Ahi, Alo, rowoff, csr_src, dinv);
    gemm_mfma<<<GB, 256, 0, stream>>>(Ahi, Alo, wsp + 4 * DIM * DIM, hA, NN);
    agg_kernel<false><<<NN, 128, 0, stream>>>(hA, hB, nullptr, nullptr, rowoff, csr_src, dinv);

    // ---- pool + MLP (atomic-free two-stage, stage 2 fused into MLP)
    dim3 pgrid(NG, PSLICE);
    pool_part<<<pgrid, 128, 0, stream>>>(hB, first, ppart);
    mlp_kernel<<<NG, 128, 0, stream>>>(ppart, first, M0w, M0b, M1w, M1b, out);
}